// Round 20
// baseline (142.406 us; speedup 1.0000x reference)
//
#include <hip/hip_runtime.h>
#include <hip/hip_fp16.h>

#define CH 256
#define HW 4096
#define K_TOP 115
#define CAND 128
#define TPAD 152   // u16 row stride: 304B; 4-row offset = 16 mod 32 -> 2-way (free)
#define NTRI 528   // 32*33/2 upper-triangle 128x128 tiles per batch
#define NTRI_H 264 // half-triangle per XCD

typedef __attribute__((ext_vector_type(8))) short short8;
typedef __attribute__((ext_vector_type(4))) float f32x4;
typedef __attribute__((ext_vector_type(4))) unsigned int u32x4;

__device__ __forceinline__ unsigned short f32_to_bf16(float f) {
  union { float f; unsigned int u; } v; v.f = f;
  unsigned int r = v.u + 0x7fffu + ((v.u >> 16) & 1u);
  return (unsigned short)(r >> 16);
}

__device__ __forceinline__ unsigned int f16key(unsigned short h) {
  return (h & 0x8000u) ? (unsigned int)((unsigned short)~h)
                       : (unsigned int)(h | 0x8000u);
}

// stored P-form: P = key15 | 0x8000, key15 = f16key - 0x4000 (no wrap:
// |corr|<=1.008 => f16key in [0x43F0,0xBC10]); bit15 always set.
__device__ __forceinline__ unsigned int f16keyP(unsigned short h) {
  return (f16key(h) + 0x4000u) & 0xffffu;
}

__device__ __forceinline__ unsigned short key2f16(unsigned int k) {
  return (k & 0x8000u) ? (unsigned short)(k ^ 0x8000u)
                       : (unsigned short)(~k & 0xffffu);
}

// ---------- kernel 1a: rn[b][p] = 1 / max(||x[b,:,p]||, eps) ----------
__global__ void norms_kernel(const float* __restrict__ x, float* __restrict__ rn) {
  int b = blockIdx.x >> 4;
  int p = ((blockIdx.x & 15) << 8) + threadIdx.x;
  const float* xb = x + (size_t)b * CH * HW + p;
  float ss = 0.f;
  #pragma unroll 8
  for (int c = 0; c < CH; ++c) { float v = xb[(size_t)c * HW]; ss += v * v; }
  rn[b * HW + p] = 1.0f / fmaxf(sqrtf(ss), 1e-12f);
}

// ---------- kernel 1b: xnT in FRAGMENT-MAJOR layout (R14: fixes TA-bound GEMM) ----------
__global__ void transpose_kernel(const float* __restrict__ x, const float* __restrict__ rn,
                                 unsigned short* __restrict__ xnT) {
  __shared__ float tile[64][65];   // [c_local][p_local]
  int blk = blockIdx.x;
  int b = blk >> 8;
  int rem = blk & 255;
  int c0 = (rem >> 6) << 6;
  int p0 = (rem & 63) << 6;
  for (int idx = threadIdx.x; idx < 64 * 64; idx += blockDim.x) {
    int c = idx >> 6, p = idx & 63;
    tile[c][p] = x[((size_t)b * CH + c0 + c) * HW + p0 + p];
  }
  __syncthreads();
  for (int E = threadIdx.x; E < 512; E += blockDim.x) {
    int lr  = E & 15;
    int lk  = (E >> 4) & 3;
    int kkl = (E >> 6) & 1;
    int pgl = E >> 7;
    int pl = pgl * 16 + lr;
    int cl = kkl * 32 + lk * 8;
    float s = rn[b * HW + p0 + pl];
    unsigned int w0, w1, w2, w3;
    w0 = (unsigned int)f32_to_bf16(tile[cl + 0][pl] * s) |
         ((unsigned int)f32_to_bf16(tile[cl + 1][pl] * s) << 16);
    w1 = (unsigned int)f32_to_bf16(tile[cl + 2][pl] * s) |
         ((unsigned int)f32_to_bf16(tile[cl + 3][pl] * s) << 16);
    w2 = (unsigned int)f32_to_bf16(tile[cl + 4][pl] * s) |
         ((unsigned int)f32_to_bf16(tile[cl + 5][pl] * s) << 16);
    w3 = (unsigned int)f32_to_bf16(tile[cl + 6][pl] * s) |
         ((unsigned int)f32_to_bf16(tile[cl + 7][pl] * s) << 16);
    u32x4 w = {w0, w1, w2, w3};
    int pg  = (p0 >> 4) + pgl;
    int kkg = (c0 >> 5) + kkl;
    *(u32x4*)(xnT + ((((size_t)b * 256 + pg) * 8 + kkg) * 64 + lk * 16 + lr) * 8) = w;
  }
}

// ---------- kernel A: symmetric Gram -> P-form u16 keys (R15 structure) ----------
__launch_bounds__(256, 4)
__global__ void gram_kernel(const unsigned short* __restrict__ xnT,
                            unsigned short* __restrict__ gkeys, int nb) {
  __shared__ unsigned short tile[128 * TPAD];
  const int tid  = threadIdx.x;
  const int lane = tid & 63, wv = tid >> 6;
  const int wj = wv >> 1, wi = wv & 1;
  const int lr = lane & 15, lk = lane >> 4;

  int bb, t;
  if (nb == 4) {
    const int xcd = blockIdx.x & 7;
    bb = xcd >> 1;
    t  = ((xcd & 1) ? NTRI_H : 0) + (blockIdx.x >> 3);
  } else {
    bb = 0;
    t  = blockIdx.x;
  }
  int it = (int)((sqrtf(8.0f * (float)t + 1.0f) - 1.0f) * 0.5f);
  while (((it + 1) * (it + 2)) / 2 <= t) ++it;
  while ((it * (it + 1)) / 2 > t) --it;
  const int jt = t - (it * (it + 1)) / 2;  // jt <= it
  const int j0 = jt * 128, i0 = it * 128;

  const short8* x8 = (const short8*)(xnT + (size_t)bb * HW * CH);
  unsigned short* gk = gkeys + (size_t)bb * HW * HW;

  f32x4 acc[4][4];
  #pragma unroll
  for (int m = 0; m < 4; ++m)
    #pragma unroll
    for (int n = 0; n < 4; ++n) acc[m][n] = (f32x4){0.f, 0.f, 0.f, 0.f};

  const int pgj = jt * 8 + wj * 4;
  const int pgi = it * 8 + wi * 4;
  #pragma unroll
  for (int kk = 0; kk < 8; ++kk) {
    short8 af[4], bf[4];
    #pragma unroll
    for (int m = 0; m < 4; ++m)
      af[m] = x8[(size_t)((pgj + m) * 8 + kk) * 64 + lane];
    #pragma unroll
    for (int n = 0; n < 4; ++n)
      bf[n] = x8[(size_t)((pgi + n) * 8 + kk) * 64 + lane];
    #pragma unroll
    for (int m = 0; m < 4; ++m)
      #pragma unroll
      for (int n = 0; n < 4; ++n)
        acc[m][n] = __builtin_amdgcn_mfma_f32_16x16x32_bf16(af[m], bf[n],
                                                            acc[m][n], 0, 0, 0);
  }

  // phase 1: P-form keys -> tile[jloc][iloc]  (D row = j, D col = i)
  #pragma unroll
  for (int m = 0; m < 4; ++m) {
    #pragma unroll
    for (int n = 0; n < 4; ++n) {
      #pragma unroll
      for (int r = 0; r < 4; ++r) {
        int jloc = wj * 64 + m * 16 + lk * 4 + r;
        int iloc = wi * 64 + n * 16 + lr;
        tile[jloc * TPAD + iloc] =
            (unsigned short)f16keyP(__half_as_ushort(__float2half(acc[m][n][r])));
      }
    }
  }
  __syncthreads();

  // store 1: rows j of gk (coalesced 16B chunks)
  #pragma unroll
  for (int itr = 0; itr < 8; ++itr) {
    int idx = itr * 256 + tid;
    int row = idx >> 4, ch = idx & 15;
    u32x4 v = *(const u32x4*)&tile[row * TPAD + ch * 8];
    *(u32x4*)(gk + (size_t)(j0 + row) * HW + i0 + ch * 8) = v;
  }

  if (it != jt) {
    __syncthreads();  // WAR: store-1 reads done before refill
    #pragma unroll
    for (int m = 0; m < 4; ++m) {
      #pragma unroll
      for (int n = 0; n < 4; ++n) {
        int il  = wi * 64 + n * 16 + lr;
        int jl0 = wj * 64 + m * 16 + lk * 4;
        unsigned long long pk =
            (unsigned long long)f16keyP(__half_as_ushort(__float2half(acc[m][n][0]))) |
            ((unsigned long long)f16keyP(__half_as_ushort(__float2half(acc[m][n][1]))) << 16) |
            ((unsigned long long)f16keyP(__half_as_ushort(__float2half(acc[m][n][2]))) << 32) |
            ((unsigned long long)f16keyP(__half_as_ushort(__float2half(acc[m][n][3]))) << 48);
        *(unsigned long long*)&tile[il * TPAD + jl0] = pk;
      }
    }
    __syncthreads();

    // store 2: mirror rows i of gk
    #pragma unroll
    for (int itr = 0; itr < 8; ++itr) {
      int idx = itr * 256 + tid;
      int row = idx >> 4, ch = idx & 15;
      u32x4 v = *(const u32x4*)&tile[row * TPAD + ch * 8];
      *(u32x4*)(gk + (size_t)(i0 + row) * HW + j0 + ch * 8) = v;
    }
  }
}

// ---------- kernel B: top-115, 2 columns/wave, packed dual-count ----------
// R19 falsified VALU-issue-bound (adding ops didn't move timing). New theory:
// per-wave serial chains (15 rounds x 6-deep ds_swizzle butterfly) dominate.
// Fix: 2 columns/wave; both counts packed in ONE u32 (cA|cB<<16, sums<=4096
// so no cross-half carry) -> one butterfly serves two columns (chain per
// column halves) and the two 128-op VALU streams interleave. Thresholds
// scalarized via readfirstlane (SALU co-issues).
__launch_bounds__(256, 4)
__global__ void select_kernel(const unsigned short* __restrict__ gkeys,
                              float* __restrict__ out, int b_base, int nb) {
  __shared__ __align__(16) unsigned short cand[8][CAND];
  __shared__ unsigned int rcnt[8][CAND];
  __shared__ unsigned int cnt[8];
  const int tid  = threadIdx.x;
  const int lane = tid & 63, wv = tid >> 6;
  int bb, cg;
  if (nb == 4) {
    const int xcd = blockIdx.x & 7;
    bb = xcd >> 1;
    cg = ((xcd & 1) << 8) + (blockIdx.x >> 3);   // [0,512)
  } else {
    bb = 0;
    cg = blockIdx.x;
  }
  const int b = b_base + bb;
  const int jA = cg * 8 + wv * 2;
  const int jB = jA + 1;

  const u32x4* cpA = (const u32x4*)(gkeys + (size_t)bb * HW * HW + (size_t)jA * HW);
  const u32x4* cpB = (const u32x4*)(gkeys + (size_t)bb * HW * HW + (size_t)jB * HW);
  u32x4 qa0 = cpA[0 * 64 + lane], qa1 = cpA[1 * 64 + lane];
  u32x4 qa2 = cpA[2 * 64 + lane], qa3 = cpA[3 * 64 + lane];
  u32x4 qa4 = cpA[4 * 64 + lane], qa5 = cpA[5 * 64 + lane];
  u32x4 qa6 = cpA[6 * 64 + lane], qa7 = cpA[7 * 64 + lane];
  u32x4 qb0 = cpB[0 * 64 + lane], qb1 = cpB[1 * 64 + lane];
  u32x4 qb2 = cpB[2 * 64 + lane], qb3 = cpB[3 * 64 + lane];
  u32x4 qb4 = cpB[4 * 64 + lane], qb5 = cpB[5 * 64 + lane];
  u32x4 qb6 = cpB[6 * 64 + lane], qb7 = cpB[7 * 64 + lane];

  unsigned int loA = 0, loB = 0;
  // peeled round bit=14: key15 >= 0x4000 <=> bit14 set
  {
    unsigned int SA = 0, SB = 0;
    #define CB14(Q, S) \
      S += (Q.x >> 14) & 0x00010001u; S += (Q.y >> 14) & 0x00010001u; \
      S += (Q.z >> 14) & 0x00010001u; S += (Q.w >> 14) & 0x00010001u;
    CB14(qa0, SA) CB14(qa1, SA) CB14(qa2, SA) CB14(qa3, SA)
    CB14(qa4, SA) CB14(qa5, SA) CB14(qa6, SA) CB14(qa7, SA)
    CB14(qb0, SB) CB14(qb1, SB) CB14(qb2, SB) CB14(qb3, SB)
    CB14(qb4, SB) CB14(qb5, SB) CB14(qb6, SB) CB14(qb7, SB)
    #undef CB14
    unsigned int c = ((SA & 0xffffu) + (SA >> 16)) |
                     (((SB & 0xffffu) + (SB >> 16)) << 16);
    c += __shfl_xor(c, 1);
    c += __shfl_xor(c, 2);
    c += __shfl_xor(c, 4);
    c += __shfl_xor(c, 8);
    c += __shfl_xor(c, 16);
    c += __shfl_xor(c, 32);
    unsigned int cc = (unsigned int)__builtin_amdgcn_readfirstlane((int)c);
    if ((cc & 0xffffu) >= K_TOP) loA = 0x4000u;
    if ((cc >> 16) >= K_TOP)     loB = 0x4000u;
  }
  // rounds bit 13..0: borrow can't cross halves (P half >= 0x8000, m <= 0x7fff)
  #pragma unroll 1
  for (int bit = 13; bit >= 0; --bit) {
    const unsigned int mmA = (loA | (1u << bit)) * 0x10001u;
    const unsigned int mmB = (loB | (1u << bit)) * 0x10001u;
    unsigned int SA = 0, SB = 0;
    #define CNTV(Q, S, MM) \
      S += ((Q.x - MM) >> 15) & 0x00010001u; S += ((Q.y - MM) >> 15) & 0x00010001u; \
      S += ((Q.z - MM) >> 15) & 0x00010001u; S += ((Q.w - MM) >> 15) & 0x00010001u;
    CNTV(qa0, SA, mmA) CNTV(qb0, SB, mmB)
    CNTV(qa1, SA, mmA) CNTV(qb1, SB, mmB)
    CNTV(qa2, SA, mmA) CNTV(qb2, SB, mmB)
    CNTV(qa3, SA, mmA) CNTV(qb3, SB, mmB)
    CNTV(qa4, SA, mmA) CNTV(qb4, SB, mmB)
    CNTV(qa5, SA, mmA) CNTV(qb5, SB, mmB)
    CNTV(qa6, SA, mmA) CNTV(qb6, SB, mmB)
    CNTV(qa7, SA, mmA) CNTV(qb7, SB, mmB)
    #undef CNTV
    unsigned int c = ((SA & 0xffffu) + (SA >> 16)) |
                     (((SB & 0xffffu) + (SB >> 16)) << 16);
    c += __shfl_xor(c, 1);
    c += __shfl_xor(c, 2);
    c += __shfl_xor(c, 4);
    c += __shfl_xor(c, 8);
    c += __shfl_xor(c, 16);
    c += __shfl_xor(c, 32);
    unsigned int cc = (unsigned int)__builtin_amdgcn_readfirstlane((int)c);
    if ((cc & 0xffffu) >= K_TOP) loA |= (1u << bit);
    if ((cc >> 16) >= K_TOP)     loB |= (1u << bit);
  }

  const int ra = wv * 2, rb = wv * 2 + 1;
  cand[ra][2 * lane]     = (unsigned short)loA;
  cand[ra][2 * lane + 1] = (unsigned short)loA;
  cand[rb][2 * lane]     = (unsigned short)loB;
  cand[rb][2 * lane + 1] = (unsigned short)loB;
  rcnt[ra][2 * lane]     = 0;
  rcnt[ra][2 * lane + 1] = 0;
  rcnt[rb][2 * lane]     = 0;
  rcnt[rb][2 * lane + 1] = 0;
  if (lane == 0) { cnt[ra] = 0; cnt[rb] = 0; }

  // scatter strictly-greater 15-bit keys (<=114 per column guaranteed)
  #define GATH(row, v, lo)                                       \
    { unsigned int _v = (v);                                     \
      if (_v > (lo)) {                                           \
        unsigned int _p = atomicAdd(&cnt[row], 1u);              \
        cand[row][_p] = (unsigned short)_v;                      \
      } }
  #define GATH4(row, Q, lo)                                      \
    GATH(row, Q.x & 0x7fffu, lo) GATH(row, (Q.x >> 16) & 0x7fffu, lo) \
    GATH(row, Q.y & 0x7fffu, lo) GATH(row, (Q.y >> 16) & 0x7fffu, lo) \
    GATH(row, Q.z & 0x7fffu, lo) GATH(row, (Q.z >> 16) & 0x7fffu, lo) \
    GATH(row, Q.w & 0x7fffu, lo) GATH(row, (Q.w >> 16) & 0x7fffu, lo)
  GATH4(ra, qa0, loA) GATH4(ra, qa1, loA) GATH4(ra, qa2, loA) GATH4(ra, qa3, loA)
  GATH4(ra, qa4, loA) GATH4(ra, qa5, loA) GATH4(ra, qa6, loA) GATH4(ra, qa7, loA)
  GATH4(rb, qb0, loB) GATH4(rb, qb1, loB) GATH4(rb, qb2, loB) GATH4(rb, qb3, loB)
  GATH4(rb, qb4, loB) GATH4(rb, qb5, loB) GATH4(rb, qb6, loB) GATH4(rb, qb7, loB)
  #undef GATH4
  #undef GATH

  __syncthreads();  // fence: scatter stores visible before u32 re-read

  // strict-greater counts (SWAR, broadcast LDS reads), dense tie ranks
  unsigned int k0A = cand[ra][2 * lane], k1A = cand[ra][2 * lane + 1];
  unsigned int k0B = cand[rb][2 * lane], k1B = cand[rb][2 * lane + 1];
  const unsigned int t0A = (k0A + 1u) * 0x10001u;
  const unsigned int t1A = (k1A + 1u) * 0x10001u;
  const unsigned int t0B = (k0B + 1u) * 0x10001u;
  const unsigned int t1B = (k1B + 1u) * 0x10001u;
  unsigned int S0A = 0, S1A = 0, S0B = 0, S1B = 0;
  {
    const u32x4* cvA = (const u32x4*)&cand[ra][0];
    const u32x4* cvB = (const u32x4*)&cand[rb][0];
    #pragma unroll
    for (int r = 0; r < 16; ++r) {
      u32x4 pA = cvA[r];
      u32x4 pB = cvB[r];
      #define GC(W, S, T) { unsigned int Pt = (W) | 0x80008000u;  \
        S += ((Pt - T) >> 15) & 0x00010001u; }
      GC(pA.x, S0A, t0A) GC(pA.x, S1A, t1A)
      GC(pA.y, S0A, t0A) GC(pA.y, S1A, t1A)
      GC(pA.z, S0A, t0A) GC(pA.z, S1A, t1A)
      GC(pA.w, S0A, t0A) GC(pA.w, S1A, t1A)
      GC(pB.x, S0B, t0B) GC(pB.x, S1B, t1B)
      GC(pB.y, S0B, t0B) GC(pB.y, S1B, t1B)
      GC(pB.z, S0B, t0B) GC(pB.z, S1B, t1B)
      GC(pB.w, S0B, t0B) GC(pB.w, S1B, t1B)
      #undef GC
    }
  }
  int g0A = (int)((S0A & 0xffffu) + (S0A >> 16));
  int g1A = (int)((S1A & 0xffffu) + (S1A >> 16));
  int g0B = (int)((S0B & 0xffffu) + (S0B >> 16));
  int g1B = (int)((S1B & 0xffffu) + (S1B >> 16));
  int r0A = g0A + (int)atomicAdd(&rcnt[ra][g0A], 1u);
  int r1A = g1A + (int)atomicAdd(&rcnt[ra][g1A], 1u);
  int r0B = g0B + (int)atomicAdd(&rcnt[rb][g0B], 1u);
  int r1B = g1B + (int)atomicAdd(&rcnt[rb][g1B], 1u);

  if (r0A < K_TOP)
    out[((size_t)b * K_TOP + r0A) * HW + jA] =
        __half2float(__ushort_as_half(key2f16(k0A + 0x4000u))) * (1.0f / 256.0f);
  if (r1A < K_TOP)
    out[((size_t)b * K_TOP + r1A) * HW + jA] =
        __half2float(__ushort_as_half(key2f16(k1A + 0x4000u))) * (1.0f / 256.0f);
  if (r0B < K_TOP)
    out[((size_t)b * K_TOP + r0B) * HW + jB] =
        __half2float(__ushort_as_half(key2f16(k0B + 0x4000u))) * (1.0f / 256.0f);
  if (r1B < K_TOP)
    out[((size_t)b * K_TOP + r1B) * HW + jB] =
        __half2float(__ushort_as_half(key2f16(k1B + 0x4000u))) * (1.0f / 256.0f);
}

extern "C" void kernel_launch(void* const* d_in, const int* in_sizes, int n_in,
                              void* d_out, int out_size, void* d_ws, size_t ws_size,
                              hipStream_t stream) {
  (void)in_sizes; (void)n_in; (void)out_size;
  const float* x = (const float*)d_in[0];
  float* out = (float*)d_out;
  float* rn = (float*)d_ws;                                       // 64 KB
  unsigned short* xnT = (unsigned short*)((char*)d_ws + 65536);   // 8 MB bf16
  const size_t GK_OFF = 65536 + (size_t)8 * 1024 * 1024;
  const size_t ONE    = (size_t)HW * HW * 2;                      // 32 MB / batch
  const size_t NEED_1 = GK_OFF + ONE;
  const size_t NEED_4 = GK_OFF + 4 * ONE;                         // 136 MB

  norms_kernel<<<64, 256, 0, stream>>>(x, rn);
  transpose_kernel<<<1024, 256, 0, stream>>>(x, rn, xnT);

  if (ws_size >= NEED_4) {
    unsigned short* gkeys = (unsigned short*)((char*)d_ws + GK_OFF);
    gram_kernel<<<4 * NTRI, 256, 0, stream>>>(xnT, gkeys, 4);
    select_kernel<<<2048, 256, 0, stream>>>(gkeys, out, 0, 4);
  } else if (ws_size >= NEED_1) {
    unsigned short* gkeys = (unsigned short*)((char*)d_ws + GK_OFF);
    for (int b = 0; b < 4; ++b) {
      gram_kernel<<<NTRI, 256, 0, stream>>>(xnT + (size_t)b * HW * CH, gkeys, 1);
      select_kernel<<<512, 256, 0, stream>>>(gkeys, out, b, 1);
    }
  }
}